// Round 1
// baseline (42.504 us; speedup 1.0000x reference)
//
#include <hip/hip_runtime.h>
#include <hip/hip_bf16.h>

// Problem shapes (fixed by setup_inputs): D=1, S=64, A=128, P=K=6, T=80
#define NS 64
#define NA 128
#define NK 6
#define NT 80
#define TILE_A 8
#define THREADS 256

// Output layout (flat concat, floats):
//   waymo_valid  [S,T,A]        655360
//   waymo_trajs  [S,T,A,K,2]    7864320
//   waymo_scores [S,A,K]        49152
//   waymo_yaw    [S,T,A,K,1]    3932160
#define OFF_TRAJ   655360
#define OFF_SCORE  (655360 + 7864320)
#define OFF_YAW    (655360 + 7864320 + 49152)

__global__ __launch_bounds__(THREADS) void waymo_post_kernel(
    const int*    __restrict__ validIn,  // [S,A] (bool -> int32)
    const float*  __restrict__ confIn,   // [1,S,A,K]
    const float2* __restrict__ posIn,    // [1,S,A,K,T] as float2
    const float*  __restrict__ yawIn,    // [1,S,A,K,T]
    const float*  __restrict__ typeIn,   // [S,A,3] one-hot
    float*        __restrict__ out)
{
    const int s   = blockIdx.y;
    const int a0  = blockIdx.x * TILE_A;
    const int tid = threadIdx.x;

    // padded LDS tiles: row stride 81 (pad +1) to break stride-80 bank aliasing
    __shared__ float2 sPos[TILE_A * NK * 81];  // [r=la*6+k][t]
    __shared__ float  sYaw[TILE_A * NK * 81];

    // ---- stage: coalesced read of 8 agents' worth of pos+yaw ----
    const size_t base = ((size_t)(s * NA + a0)) * NK * NT;  // float2 units (pos) / float units (yaw)
    for (int i = tid; i < TILE_A * NK * NT; i += THREADS) {
        int r = i / NT;           // la*6+k
        int t = i - r * NT;
        sPos[r * 81 + t] = posIn[base + i];
        sYaw[r * 81 + t] = yawIn[base + i];
    }
    __syncthreads();

    float*  outV  = out;                    // [S,T,A]
    float2* outT  = (float2*)(out + OFF_TRAJ);  // [S,T,A,K] of float2
    float*  outSc = out + OFF_SCORE;        // [S,A,K]
    float*  outY  = out + OFF_YAW;          // [S,T,A,K]

    // ---- scores + NMS: 32 lanes per agent ----
    {
        const int la   = tid >> 5;    // agent within tile
        const int lane = tid & 31;
        const int a    = a0 + la;
        const int p    = lane >> 1;   // pair slot 0..15 (15 used)
        const int half = lane & 1;    // time half

        const size_t sa = (size_t)s * NA + a;
        const float th = 2.5f * typeIn[sa * 3 + 0]
                       + 1.0f * typeIn[sa * 3 + 1]
                       + 1.5f * typeIn[sa * 3 + 2];

        // pair slot -> (i,j), i<j, row-major upper triangle of 6x6
        int pi, pj;
        if      (p < 5)  { pi = 0; pj = p + 1; }
        else if (p < 9)  { pi = 1; pj = p - 3; }
        else if (p < 12) { pi = 2; pj = p - 6; }
        else if (p < 14) { pi = 3; pj = p - 8; }
        else             { pi = 4; pj = 5;     }

        const int rI = la * NK + pi, rJ = la * NK + pj;
        float dsum = 0.f;
        for (int t = half * 40; t < half * 40 + 40; ++t) {
            float2 u = sPos[rI * 81 + t];
            float2 v = sPos[rJ * 81 + t];
            float dx = u.x - v.x, dy = u.y - v.y;
            dsum += sqrtf(dx * dx + dy * dy);
        }
        dsum += __shfl_xor(dsum, 1);
        const bool within = (dsum / 80.0f) < th;
        const bool predb  = (half == 0) && (p < 15) && within;
        unsigned long long bal = __ballot(predb);
        // wave holds 2 agents; this agent's 32 bits:
        unsigned mask32 = (unsigned)(bal >> (tid & 32));

        if (lane == 0) {
            // softmax over K=6 (stable, like jax.nn.softmax)
            float c[NK];
            float mx = -3e38f;
            for (int q = 0; q < NK; ++q) { c[q] = confIn[sa * NK + q]; mx = fmaxf(mx, c[q]); }
            float ssum = 0.f;
            for (int q = 0; q < NK; ++q) { c[q] = expf(c[q] - mx); ssum += c[q]; }
            for (int q = 0; q < NK; ++q) c[q] /= ssum;
            // reference re-normalizes again
            ssum = 0.f;
            for (int q = 0; q < NK; ++q) ssum += c[q];
            for (int q = 0; q < NK; ++q) c[q] /= ssum;

            // stable descending argsort (selection; strict > keeps earliest on ties)
            int ord[NK]; bool used[NK];
            for (int q = 0; q < NK; ++q) used[q] = false;
            for (int st = 0; st < NK; ++st) {
                int best = 0; float bv = -3e38f;
                for (int q = 0; q < NK; ++q)
                    if (!used[q] && c[q] > bv) { bv = c[q]; best = q; }
                used[best] = true; ord[st] = best;
            }

            float cur[NK];
            for (int q = 0; q < NK; ++q) cur[q] = c[q];

            if (validIn[sa] != 0) {
                for (int st = 0; st < NK; ++st) {
                    int k = ord[st];
                    float ck = cur[k];
                    bool any = false;
                    for (int j = 0; j < NK; ++j) {
                        if (j == k) continue;
                        int lo = j < k ? j : k;
                        int hi = j < k ? k : j;
                        int pidx = lo * 5 - (lo * (lo - 1)) / 2 + (hi - lo - 1);
                        if (((mask32 >> (2 * pidx)) & 1u) && (cur[j] > ck)) any = true;
                    }
                    if (any) cur[k] = 0.001f;
                }
            }

            // renormalize, then softmax(log(s)/0.5) == s^2 / sum(s^2)
            float tsum = 0.f;
            for (int q = 0; q < NK; ++q) tsum += cur[q];
            float w[NK]; float wsum = 0.f;
            for (int q = 0; q < NK; ++q) {
                float qq = cur[q] / tsum;
                w[q] = qq * qq; wsum += w[q];
            }
            for (int q = 0; q < NK; ++q) outSc[sa * NK + q] = w[q] / wsum;
        }
    }

    // ---- transpose writes: trajs + yaw (coalesced 384B/192B runs) ----
    for (int o = tid; o < TILE_A * NK * NT; o += THREADS) {
        int t  = o / (TILE_A * NK);
        int r  = o - t * (TILE_A * NK);   // la*6+k in output order
        int la = r / NK;
        int k  = r - la * NK;
        size_t oidx = ((size_t)(s * NT + t) * NA + (a0 + la)) * NK + k;
        outT[oidx] = sPos[r * 81 + t];
        outY[oidx] = sYaw[r * 81 + t];
    }

    // ---- valid broadcast ----
    for (int o = tid; o < NT * TILE_A; o += THREADS) {
        int t  = o >> 3;
        int la = o & 7;
        outV[(size_t)(s * NT + t) * NA + a0 + la] =
            (validIn[(size_t)s * NA + a0 + la] != 0) ? 1.0f : 0.0f;
    }
}

extern "C" void kernel_launch(void* const* d_in, const int* in_sizes, int n_in,
                              void* d_out, int out_size, void* d_ws, size_t ws_size,
                              hipStream_t stream) {
    const int*    validIn = (const int*)d_in[0];
    const float*  confIn  = (const float*)d_in[1];
    const float2* posIn   = (const float2*)d_in[2];
    const float*  yawIn   = (const float*)d_in[3];
    const float*  typeIn  = (const float*)d_in[4];
    float* out = (float*)d_out;

    dim3 grid(NA / TILE_A, NS);  // (16, 64)
    waymo_post_kernel<<<grid, THREADS, 0, stream>>>(validIn, confIn, posIn, yawIn, typeIn, out);
}